// Round 10
// baseline (305.188 us; speedup 1.0000x reference)
//
#include <hip/hip_runtime.h>

#define B_    16
#define T_    8
#define K_    64
#define COUT  128
#define CIN   128
#define H_    64
#define W_    64
#define WSZ   (COUT*CIN*5*5)        // 409600 per-k (and per-b) weight elems

typedef __bf16 bf16x8 __attribute__((ext_vector_type(8)));
typedef float  f32x4  __attribute__((ext_vector_type(4)));
typedef unsigned int u32;

static __device__ __forceinline__ unsigned short f2bf(float f) {
    unsigned int u = __builtin_bit_cast(unsigned int, f);
    unsigned int r = (u + 0x7FFFu + ((u >> 16) & 1u)) >> 16;
    return (unsigned short)r;
}

static __device__ __forceinline__ unsigned int pack2(float lo, float hi) {
    return (unsigned int)f2bf(lo) | ((unsigned int)f2bf(hi) << 16);
}

// ---------------------------------------------------------------------------
// prep kernel — lp role ONLY (R0-exact lp code; xtrans eliminated: conv now
// stages x directly). Grid 512 blocks: all CUs get 2 lp blocks from t=0.
// ---------------------------------------------------------------------------
__global__ __launch_bounds__(256) void prep_kernel(const float* __restrict__ Wb,
                                                   const float* __restrict__ tf,
                                                   unsigned short* __restrict__ lpF) {
    __shared__ __align__(16) char smem[30720];
    int tid = threadIdx.x;

    // lpF[b][tap][kc(4)][wm(2)][mt(4)][lane(64)][j(8)]  (bf16)
    //   o = wm*64 + mt*16 + (lane&15), c = kc*32 + (lane>>4)*8 + j
    float* cs          = (float*)smem;                       // 4 KB
    unsigned short* lt = (unsigned short*)(smem + 4096);     // 25.6 KB

    int o = blockIdx.x >> 2;      // 0..127
    int s = blockIdx.x & 3;       // c chunk: c in [32s, 32s+32)

    // coef[b,k] = mean_t tf[b,t,k]
    {
        int idx = tid;
#pragma unroll
        for (int r = 0; r < 4; ++r, idx += 256) {
            int b = idx >> 6, k = idx & 63;
            float sum = 0.f;
#pragma unroll
            for (int t = 0; t < T_; ++t) sum += tf[(b * T_ + t) * K_ + k];
            cs[idx] = sum * 0.125f;
        }
    }
    __syncthreads();

    if (tid < 200) {
        int base = o * 3200 + s * 800 + tid * 4;
        float4 acc[B_];
#pragma unroll
        for (int b = 0; b < B_; ++b) acc[b] = make_float4(0.f, 0.f, 0.f, 0.f);

#pragma unroll 4
        for (int k = 0; k < K_; ++k) {
            const float4 wv = *(const float4*)(Wb + (size_t)k * WSZ + base);
#pragma unroll
            for (int b = 0; b < B_; ++b) {
                float c = cs[b * K_ + k];
                acc[b].x += c * wv.x;
                acc[b].y += c * wv.y;
                acc[b].z += c * wv.z;
                acc[b].w += c * wv.w;
            }
        }
        unsigned int* ltw = (unsigned int*)lt;
#pragma unroll
        for (int b = 0; b < B_; ++b) {
            ltw[b * 400 + tid * 2]     = pack2(acc[b].x, acc[b].y);
            ltw[b * 400 + tid * 2 + 1] = pack2(acc[b].z, acc[b].w);
        }
    }
    __syncthreads();

    // fragment-ordered writeout: wm,mt,n16 fixed per block; quad varies
    int wm = o >> 6, mt = (o >> 4) & 3, n16 = o & 15;
    for (int it = tid; it < 1600; it += 256) {
        int b = it / 100;
        int r = it - b * 100;
        int tap = r >> 2;
        int quad = r & 3;
        unsigned short v[8];
#pragma unroll
        for (int j = 0; j < 8; ++j)
            v[j] = lt[b * 800 + (quad * 8 + j) * 25 + tap];
        size_t off = (size_t)b * 409600
                   + (size_t)((((tap * 4 + s) * 2 + wm) * 4 + mt) * 512
                              + quad * 128 + n16 * 8);
        *(uint4*)(lpF + off) = *(const uint4*)v;
    }
}

// ---------------------------------------------------------------------------
// Conv as 25 shifted GEMMs, bf16 MFMA 16x16x32, fp32 accum.
// CHANGE vs R9: xtrans FOLDED IN. Staging reads x (fp32 NCHW, L3-resident)
// directly: per (c-pair cp, w-quad wq) thread, 2 coalesced float4 loads
// (16 lanes x 16B = 256B runs), pack2 -> 4 ds_write_b32. LDS stride 40->42
// shorts (gcd(21,32)=1) keeps write and b128-read patterns <=2-way banked.
// Halo columns (ww 0,1,66,67) and OOB rows pre-zeroed ONCE; per-kc staging
// writes only valid cells. Compute loop: R9 rolling-window (j-outer,
// 3-row register window, 120 b128-reads/wave/kc), constants for stride 42.
// ---------------------------------------------------------------------------
__global__ __launch_bounds__(256) void conv_mfma(const float* __restrict__ x,
                                                 const unsigned short* __restrict__ lpF,
                                                 float* __restrict__ out) {
    int bid = blockIdx.x;
    int b  = (bid & 7) | (((bid >> 3) & 1) << 3);   // XCD-local batch
    int h0 = (bid >> 4) << 1;                       // row pair

    int tid  = threadIdx.x;
    int lane = tid & 63, wq4 = tid >> 6;      // wq4: o-quarter 0..3
    int n16 = lane & 15, quad = lane >> 4;

    __shared__ __align__(16) unsigned short xs[408 * 42];   // 34272 B

    f32x4 acc[2][8];
#pragma unroll
    for (int mt = 0; mt < 2; ++mt)
#pragma unroll
        for (int nt = 0; nt < 8; ++nt) acc[mt][nt] = (f32x4){0.f, 0.f, 0.f, 0.f};

    const unsigned short* lpW = lpF + (size_t)b * 409600
                              + (wq4 >> 1) * 2048 + (wq4 & 1) * 1024 + lane * 8;

    // pre-zero whole tile once: halo cols + OOB rows stay zero for all kc
    {
        u32* z = (u32*)xs;
        for (int i = tid; i < (408 * 42) / 2; i += 256) z[i] = 0u;
    }

    int cp = tid >> 4;        // 0..15: c-pair within 32-c chunk
    int wq = tid & 15;        // 0..15: w quad (gw = wq*4..wq*4+3)

    for (int kc = 0; kc < 4; ++kc) {
        int kcOff = kc * 32;
        int kcB   = kc * 4096;
        __syncthreads();                       // previous chunk's readers done
        // stage rows h0-2..h0+3 (valid only), transpose fp32 NCHW -> bf16 [row][w][c]
        const float* xc = x + ((size_t)(b * CIN + kcOff + 2 * cp) * H_) * W_ + wq * 4;
#pragma unroll
        for (int rr = 0; rr < 6; ++rr) {
            int gr = h0 - 2 + rr;
            if ((unsigned)gr < 64u) {
                const float* x0 = xc + (size_t)gr * W_;
                float4 a  = *(const float4*)x0;
                float4 c4 = *(const float4*)(x0 + H_ * W_);
                int wwb = rr * 68 + wq * 4 + 2;
                *(u32*)&xs[(wwb + 0) * 42 + 2 * cp] = pack2(a.x, c4.x);
                *(u32*)&xs[(wwb + 1) * 42 + 2 * cp] = pack2(a.y, c4.y);
                *(u32*)&xs[(wwb + 2) * 42 + 2 * cp] = pack2(a.z, c4.z);
                *(u32*)&xs[(wwb + 3) * 42 + 2 * cp] = pack2(a.w, c4.w);
            }
        }
        __syncthreads();

#pragma unroll
        for (int j = 0; j < 5; ++j) {
            // cell (rr,ww,cc) at xs[(rr*68+ww)*42+cc]; this wave's col = n16+j
            const unsigned short* rp = &xs[(n16 + j) * 42 + quad * 8];

            bf16x8 R0[4], R1[4], R2[4];       // rolling rows i, i+1, i+2
            bf16x8 A0[2], A1[2];
#pragma unroll
            for (int nt = 0; nt < 4; ++nt) R0[nt] = *(const bf16x8*)(rp + nt * 672);
#pragma unroll
            for (int nt = 0; nt < 4; ++nt) R1[nt] = *(const bf16x8*)(rp + 2856 + nt * 672);
            {
                const unsigned short* ap = lpW + j * 16384 + kcB;   // tap (0,j)
                A0[0] = *(const bf16x8*)(ap);
                A0[1] = *(const bf16x8*)(ap + 512);
            }
#pragma unroll
            for (int i = 0; i < 5; ++i) {
                if (i < 4) {
                    const unsigned short* rpn = rp + (i + 2) * 2856;
#pragma unroll
                    for (int nt = 0; nt < 4; ++nt)
                        R2[nt] = *(const bf16x8*)(rpn + nt * 672);
                    const unsigned short* apn = lpW + ((i + 1) * 5 + j) * 16384 + kcB;
                    A1[0] = *(const bf16x8*)(apn);
                    A1[1] = *(const bf16x8*)(apn + 512);
                }
                // acc[mt][nt]   += A0[mt] x R0[nt]   (output row h0)
                // acc[mt][nt+4] += A0[mt] x R1[nt]   (output row h0+1)
#pragma unroll
                for (int mt = 0; mt < 2; ++mt)
#pragma unroll
                    for (int nt = 0; nt < 4; ++nt) {
                        acc[mt][nt] = __builtin_amdgcn_mfma_f32_16x16x32_bf16(
                            A0[mt], R0[nt], acc[mt][nt], 0, 0, 0);
                        acc[mt][nt + 4] = __builtin_amdgcn_mfma_f32_16x16x32_bf16(
                            A0[mt], R1[nt], acc[mt][nt + 4], 0, 0, 0);
                    }
                // rotate window (static, unrolled -> register renaming)
#pragma unroll
                for (int nt = 0; nt < 4; ++nt) { R0[nt] = R1[nt]; R1[nt] = R2[nt]; }
                A0[0] = A1[0]; A0[1] = A1[1];
            }
        }
    }

    // epilogue: o = wq4*32 + mt*16 + quad*4 + r; h = h0+(nt>>2); w = (nt&3)*16+n16
    float* outb = out + (size_t)b * (COUT * H_ * W_);
#pragma unroll
    for (int mt = 0; mt < 2; ++mt) {
#pragma unroll
        for (int nt = 0; nt < 8; ++nt) {
#pragma unroll
            for (int r = 0; r < 4; ++r) {
                int o = wq4 * 32 + mt * 16 + quad * 4 + r;
                int h = h0 + (nt >> 2);
                int w = (nt & 3) * 16 + n16;
                outb[(size_t)o * (H_ * W_) + (size_t)h * W_ + w] = acc[mt][nt][r];
            }
        }
    }
}

// ---------------------------------------------------------------------------
extern "C" void kernel_launch(void* const* d_in, const int* in_sizes, int n_in,
                              void* d_out, int out_size, void* d_ws, size_t ws_size,
                              hipStream_t stream) {
    const float* x  = (const float*)d_in[0];   // (16,128,64,64)
    const float* tf = (const float*)d_in[1];   // (16,8,64)
    const float* Wb = (const float*)d_in[2];   // (64,128,128,5,5)
    float* out = (float*)d_out;                // (16,128,64,64) fp32

    // ws: lpF bf16 fragment-ordered 16*409600 = 13.1 MB
    unsigned short* lpF = (unsigned short*)d_ws;

    prep_kernel<<<512, 256, 0, stream>>>(Wb, tf, lpF);
    conv_mfma  <<<512, 256, 0, stream>>>(x, lpF, out);
}